// Round 12
// baseline (126.540 us; speedup 1.0000x reference)
//
#include <hip/hip_runtime.h>
#include <math.h>

// Preisach hysteresis, SINGLE kernel with role-partitioned blocks.
// Facts driving this design (measured): 1-block builds cost ~60us of one-CU
// work (r5/r6/r11); grid.sync costs ~170us (r10); round-9's 3-node pipeline
// = ~10us work + ~15us node overhead. So: one node, distributed build,
// flag-based producer/consumer sync (no grid.sync), and the main scan is
// table-free until its deferred end-of-scan lookups -- by which time the
// build is done, so the wait is ~0.
//
// Block roles (grid = 50 + 51 + 1024 = 1125, 256 thr each):
//  [0,50)    rows:  R[j][b] row prefixes -> Cg1 (round-9 validated scan),
//                   then release-store MAGIC to rowflags[bid].
//  [50,101)  cols:  ballot-spin rowflags, col-prefix Cg1 -> Cg2 (separate
//                   buffer => replays are idempotent even with stale flags),
//                   release colflags.
//  [101,1125) main: wave-per-t backward-record scan (round-9 validated),
//                   chunk stats computed locally from staged h; spin-checks
//                   colflags only right before the deferred table lookups.
//
// Table: C[a][b] = sum_{alpha_idx<a, beta_idx<b, beta<=alpha} softplus(raw),
// a,b in [0,L], row-major stride SP=202. packed p(i,j)=L*i-i(i-1)/2+(j-i).

#define HYST_MAGIC 0x5A17C0DE

__device__ __forceinline__ float softplus_f(float x) {
    return fmaxf(x, 0.0f) + log1pf(expf(-fabsf(x)));
}

__global__ __launch_bounds__(256, 4) void hyst_one(
    const float* __restrict__ h,
    const float* __restrict__ mesh,
    const float* __restrict__ raw,
    const float* __restrict__ scale,
    const float* __restrict__ offset,
    float* __restrict__ out,
    float* __restrict__ Cg1,
    float* __restrict__ Cg2,
    int* __restrict__ rowflags,
    int* __restrict__ colflags,
    int T, int L, int n, int nrowblk, int ncolblk)
{
    extern __shared__ float sm[];
    const int W  = L + 1;
    const int SP = (W + 1) & ~1;
    const int nc = (T + 63) >> 6;

    const int tid  = threadIdx.x;
    const int lane = tid & 63;
    const int wid  = tid >> 6;
    const int nwv  = blockDim.x >> 6;   // 4
    const int bid  = blockIdx.x;

    // ================= ROWS =================
    if (bid < nrowblk) {
        const int j = bid * nwv + wid;
        if (j < L) {
            float* row = Cg1 + (size_t)(j + 1) * SP;
            float s[4];
            float run = 0.0f;
#pragma unroll
            for (int q = 0; q < 4; ++q) {
                const int i = 4 * lane + q;          // beta index
                float d = 0.0f;
                if (i <= j) {
                    const int p = L * i - (i * (i - 1)) / 2 + (j - i);
                    d = softplus_f(raw[p]);
                }
                run += d; s[q] = run;                // lane-local inclusive
            }
            float x = run;
            for (int o = 1; o < 64; o <<= 1) {
                const float tv = __shfl_up(x, o);
                if (lane >= o) x += tv;
            }
            const float excl = x - run;
#pragma unroll
            for (int q = 0; q < 4; ++q) {
                const int i = 4 * lane + q;
                if (i <= j) row[i + 1] = excl + s[q];
            }
            const float total = __shfl(x, 63);
            for (int b = j + 2 + lane; b <= L; b += 64) row[b] = total;
            if (lane == 0) row[0] = 0.0f;
        }
        __syncthreads();
        __threadfence();
        if (tid == 0)
            __hip_atomic_store(&rowflags[bid], HYST_MAGIC,
                               __ATOMIC_RELEASE, __HIP_MEMORY_SCOPE_AGENT);
        return;
    }

    // ================= COLS =================
    if (bid < nrowblk + ncolblk) {
        // per-wave ballot spin on all row flags (bounded; in practice ~2us)
        long cnt = 0;
        for (;;) {
            const bool pending = (lane < nrowblk) &&
                (__hip_atomic_load(&rowflags[lane], __ATOMIC_ACQUIRE,
                                   __HIP_MEMORY_SCOPE_AGENT) != HYST_MAGIC);
            if (__ballot(pending) == 0ull) break;
            __builtin_amdgcn_s_sleep(8);
            if (++cnt > (1L << 22)) break;   // safety bound: never hang
        }
        __threadfence();

        const int b = (bid - nrowblk) * nwv + wid;
        if (b < W) {
            float v[4];
            float run = 0.0f;
#pragma unroll
            for (int q = 0; q < 4; ++q) {
                const int a = 1 + 4 * lane + q;
                const float d = (a <= L) ? Cg1[(size_t)a * SP + b] : 0.0f;
                run += d; v[q] = run;
            }
            float x = run;
            for (int o = 1; o < 64; o <<= 1) {
                const float tv = __shfl_up(x, o);
                if (lane >= o) x += tv;
            }
            const float excl = x - run;
#pragma unroll
            for (int q = 0; q < 4; ++q) {
                const int a = 1 + 4 * lane + q;
                if (a <= L) Cg2[(size_t)a * SP + b] = excl + v[q];
            }
            if (lane == 0) Cg2[b] = 0.0f;    // row a=0 of the table
        }
        __syncthreads();
        __threadfence();
        if (tid == 0)
            __hip_atomic_store(&colflags[bid - nrowblk], HYST_MAGIC,
                               __ATOMIC_RELEASE, __HIP_MEMORY_SCOPE_AGENT);
        return;
    }

    // ================= MAIN =================
    float* lh  = sm;          // T floats
    float* us  = sm + T;      // nc
    float* dsm = us + nc;     // nc

    const int mbid = bid - (nrowblk + ncolblk);
    const int t = mbid * nwv + wid;     // always < T (exact mapping)

    // stage h[0..tmax] into LDS
    const int tmax = min(T - 1, (mbid + 1) * nwv - 1);
    const int nh4  = (tmax + 4) >> 2;
    const float4* h4 = (const float4*)h;
    float4* lh4 = (float4*)lh;
    for (int k = tid; k < nh4; k += blockDim.x) lh4[k] = h4[k];

    // xs levels: lane holds levels lane, +64, +128, +192
    float xsr[4];
#pragma unroll
    for (int k = 0; k < 4; ++k) {
        const int jj = lane + 64 * k;
        xsr[k] = (jj < L) ? mesh[2 * jj + 1] : 2.0f;  // 2.0 never matches
    }
    __syncthreads();

    // local per-chunk stats from staged h (only chunks below own top chunk)
    const int ncf = tmax >> 6;
    for (int c = wid; c < ncf; c += nwv) {
        const int i = (c << 6) + lane;
        const float hv = lh[i];
        const float hp = (i > 0) ? lh[i - 1] : 0.0f;
        float mu = (hv > hp) ? hv : -1.0f;
        float md = (hv < hp) ? hv : 2.0f;
        for (int o = 1; o < 64; o <<= 1) {
            mu = fmaxf(mu, __shfl_xor(mu, o));
            md = fminf(md, __shfl_xor(md, o));
        }
        if (lane == 0) { us[c] = mu; dsm[c] = md; }
    }
    __syncthreads();

    float u_max = -1.0f, d_min = 2.0f;
    int Acov = 0, Bcov = L;
    int nrec = 0;                 // wave-uniform
    int r_up = 0, r_lo = 0, r_Ap = 0, r_Bp = 0;   // per-lane record slot
    float acc = 0.0f;             // per-lane deferred contributions
    bool tready = false;

    auto ensure_ready = [&]() {
        if (tready) return;
        long cnt = 0;
        for (;;) {
            const bool pending = (lane < ncolblk) &&
                (__hip_atomic_load(&colflags[lane], __ATOMIC_ACQUIRE,
                                   __HIP_MEMORY_SCOPE_AGENT) != HYST_MAGIC);
            if (__ballot(pending) == 0ull) break;
            __builtin_amdgcn_s_sleep(8);
            if (++cnt > (1L << 22)) break;   // safety bound
        }
        __threadfence();
        tready = true;
    };
    auto flushrec = [&]() {
        ensure_ready();
        if (lane < nrec) {
            float contrib;
            if (r_up) {
                contrib = Cg2[r_lo * SP + r_Bp] - Cg2[r_Ap * SP + r_Bp];
            } else {
                contrib = -((Cg2[L * SP + r_Bp] - Cg2[L * SP + r_lo])
                          - (Cg2[r_Ap * SP + r_Bp] - Cg2[r_Ap * SP + r_lo]));
            }
            acc += contrib;
        }
        nrec = 0;
    };
    auto count_le = [&](float v) -> int {
        return __popcll(__ballot(xsr[0] <= v)) + __popcll(__ballot(xsr[1] <= v))
             + __popcll(__ballot(xsr[2] <= v)) + __popcll(__ballot(xsr[3] <= v));
    };
    auto count_lt = [&](float v) -> int {
        return __popcll(__ballot(xsr[0] < v)) + __popcll(__ballot(xsr[1] < v))
             + __popcll(__ballot(xsr[2] < v)) + __popcll(__ballot(xsr[3] < v));
    };
    auto process_chunk = [&](int c) {
        const int i = (c << 6) + lane;      // i <= ct*64+63 <= tmax
        const float hv = lh[i];
        const float hp = (i > 0) ? lh[i - 1] : 0.0f;
        const bool valid = (i <= t);
        const bool isup = valid && (hv > hp);
        const bool isdn = valid && (hv < hp);
        unsigned long long mup = __ballot(isup && hv > u_max);
        unsigned long long mdn = __ballot(isdn && hv < d_min);
        unsigned long long m = mup | mdn;
        while (m) {
            const int rl = 63 - __builtin_clzll(m);   // largest i first
            const float v = __shfl(hv, rl);
            if ((mup >> rl) & 1ull) {
                u_max = v;
                const int lo = count_le(v);
                if (lo > Acov) {
                    if (lane == nrec) { r_up = 1; r_lo = lo; r_Ap = Acov; r_Bp = Bcov; }
                    ++nrec;
                    Acov = lo;
                    if (nrec == 64) flushrec();
                }
            } else {
                d_min = v;
                const int lo = count_lt(v);
                if (lo < Bcov) {
                    if (lane == nrec) { r_up = 0; r_lo = lo; r_Ap = Acov; r_Bp = Bcov; }
                    ++nrec;
                    Bcov = lo;
                    if (nrec == 64) flushrec();
                }
            }
            const unsigned long long below =
                (rl == 0) ? 0ull : ((1ull << rl) - 1ull);
            mup = __ballot(isup && hv > u_max) & below;
            mdn = __ballot(isdn && hv < d_min) & below;
            m = mup | mdn;
        }
    };

    const int ct = t >> 6;
    process_chunk(ct);  // partial top chunk (valid mask), exact

    for (int g = (ct - 1) >> 6; g >= 0; --g) {   // ct==0 -> skipped
        if (Acov >= L || Bcov <= 0) break;
        const int cbase = g << 6;
        const int c = cbase + lane;
        const bool act = (c < ct);
        const float vu = act ? us[c] : -1.0f;
        const float vd = act ? dsm[c] : 2.0f;
        // suffix scans (higher lanes = later chunks in backward order)
        float su = vu, sd = vd;
        for (int o = 1; o < 64; o <<= 1) {
            su = fmaxf(su, __shfl_down(su, o));
            sd = fminf(sd, __shfl_down(sd, o));
        }
        float sue = __shfl_down(su, 1);
        float sde = __shfl_down(sd, 1);
        if (lane == 63) { sue = -1.0f; sde = 2.0f; }
        const bool enter = act && ((vu > fmaxf(u_max, sue)) ||
                                   (vd < fminf(d_min, sde)));
        unsigned long long em = __ballot(enter);
        while (em) {
            const int rl = 63 - __builtin_clzll(em);
            process_chunk(cbase + rl);
            em &= ~(1ull << rl);
            if (Acov >= L || Bcov <= 0) break;
        }
    }

    flushrec();
    ensure_ready();
    // leftover region keeps initial -1
    if (lane == 0) acc -= Cg2[L * SP + Bcov] - Cg2[Acov * SP + Bcov];
    for (int o = 1; o < 64; o <<= 1) acc += __shfl_xor(acc, o);
    if (lane == 0) out[t] = scale[0] * (acc / (float)n) + offset[0];
}

extern "C" void kernel_launch(void* const* d_in, const int* in_sizes, int n_in,
                              void* d_out, int out_size, void* d_ws, size_t ws_size,
                              hipStream_t stream) {
    const float* h      = (const float*)d_in[0];
    const float* mesh   = (const float*)d_in[1];
    const float* raw    = (const float*)d_in[2];
    const float* scale  = (const float*)d_in[3];
    const float* offset = (const float*)d_in[4];
    float* out = (float*)d_out;

    const int T = in_sizes[0];
    const int n = in_sizes[2];
    const int L = (int)((sqrt(8.0 * (double)n + 1.0) - 1.0) / 2.0 + 0.5);
    const int W = L + 1;
    const int SP = (W + 1) & ~1;
    const int nc = (T + 63) / 64;
    const int nwv = 4;                          // 256 threads = 4 waves

    // d_ws layout: Cg1 | Cg2 | rowflags | colflags
    float* Cg1 = (float*)d_ws;
    float* Cg2 = Cg1 + (size_t)W * SP;
    int*   rowflags = (int*)(Cg2 + (size_t)W * SP);
    const int nrowblk = (L + nwv - 1) / nwv;    // 50
    const int ncolblk = (W + nwv - 1) / nwv;    // 51
    int*   colflags = rowflags + nrowblk;

    const int nmain = (T + nwv - 1) / nwv;      // 1024
    const int grid = nrowblk + ncolblk + nmain; // 1125
    const size_t shmem = (size_t)(T + 2 * nc) * sizeof(float);  // ~16.9 KB

    hipLaunchKernelGGL(hyst_one, dim3(grid), dim3(256), shmem, stream,
                       h, mesh, raw, scale, offset, out, Cg1, Cg2,
                       rowflags, colflags, T, L, n, nrowblk, ncolblk);
}